// Round 8
// baseline (665.604 us; speedup 1.0000x reference)
//
#include <hip/hip_runtime.h>
#include <hip/hip_cooperative_groups.h>
#include <stdint.h>

namespace cg = cooperative_groups;

#define NBINS 256
#define HW    (512 * 512)
#define NIMG  64
#define GRID  1024  // cooperative: 16 blocks (segments) per image, 4 blocks/CU
#define SEGS  16    // segments per image
#define TILES 16    // 1024-px tiles per segment
#define MMB   64    // fallback minmax/binarize blocks per image
#define HB    32    // fallback hist blocks per image
#define RB 0
#define GB 1032
#define BB 2064
#define STW 3096   // SoA staging words (12.4 KB)
#define FINV 0.00390625  // 2^-8, exact

// f64 grayscale, exact op order verified bit-exact vs np reference (rounds 3-7):
__device__ __forceinline__ double gray_of(float r, float g, float b) {
    return fma((double)b, (double)0.1140f,
           fma((double)g, (double)0.5870f,
               (double)r * (double)0.2989f));
}

// Stage one 1024-px tile (768 float4, fully lane-coalesced loads) into SoA LDS.
__device__ __forceinline__ void stage3(const float4* __restrict__ xv, int64_t tile4,
                                       float* __restrict__ st, int tid) {
    #pragma unroll
    for (int k = 0; k < 3; ++k) {
        const int q = k * 256 + tid;
        const float4 v = xv[tile4 + q];
        const int f0 = q * 4;
        int p = (int)(((unsigned)f0 * 21846u) >> 16);  // f0/3
        int c = f0 - 3 * p;                            // f0%3
        const float e[4] = {v.x, v.y, v.z, v.w};
        #pragma unroll
        for (int j = 0; j < 4; ++j) {
            const int base = (c == 0) ? RB : ((c == 1) ? GB : BB);
            st[base + p] = e[j];
            if (++c == 3) { c = 0; ++p; }
        }
    }
}

__device__ __forceinline__ int bin_of(double g, double mn, double s) {
    int id = (int)__dmul_rn(__dsub_rn(g, mn), s);  // trunc = astype(int32)
    return id < 0 ? 0 : (id > 255 ? 255 : id);
}

// ============================ cooperative fused kernel ============================
__global__ __launch_bounds__(256, 4) void k_fused(const float* __restrict__ x,
        double* __restrict__ mm_part, unsigned* __restrict__ hist_part,
        double* __restrict__ thr, float* __restrict__ out) {
    __shared__ __align__(16) unsigned char smem[STW * 4];   // 12384 B union
    __shared__ double sdm[2];
    __shared__ double smn[4], smx[4];
    float*    st  = (float*)smem;
    unsigned* lh  = (unsigned*)smem;
    float*    bst = (float*)smem;
    double*   hh  = (double*)smem;            // otsu: h[256]
    double*   w2s = (double*)(smem + 2048);
    double*   m2s = (double*)(smem + 4096);
    double*   vv  = (double*)(smem + 6144);

    const int tid = threadIdx.x;
    const int bid = blockIdx.x;
    const int img = bid >> 4;
    const int seg = bid & 15;
    const int64_t img4 = (int64_t)img * (HW * 3 / 4);
    const int64_t seg4 = img4 + (int64_t)(seg * TILES) * 768;
    const float4* xv = (const float4*)x;
    float4* ov = (float4*)out;
    cg::grid_group grid = cg::this_grid();

    // ---- phase 1: read x once; fid -> registers; block min/max partial ----
    unsigned long long fp[TILES];   // 64 px/thread as 16x(4 packed u16)
    double mn = 1e300, mx = -1e300;
    #pragma unroll
    for (int it = 0; it < TILES; ++it) {
        stage3(xv, seg4 + (int64_t)it * 768, st, tid);
        __syncthreads();
        const float4 R = *(const float4*)&st[RB + 4 * tid];
        const float4 G = *(const float4*)&st[GB + 4 * tid];
        const float4 B = *(const float4*)&st[BB + 4 * tid];
        const double g0 = gray_of(R.x, G.x, B.x), g1 = gray_of(R.y, G.y, B.y),
                     g2 = gray_of(R.z, G.z, B.z), g3 = gray_of(R.w, G.w, B.w);
        mn = fmin(mn, fmin(fmin(g0, g1), fmin(g2, g3)));
        mx = fmax(mx, fmax(fmax(g0, g1), fmax(g2, g3)));
        // fid = trunc(g*256): power-of-two scale is EXACT in f64 ->
        // g in [fid/256,(fid+1)/256) with exact endpoints (round-7 proof).
        const unsigned long long f0 = (unsigned long long)(unsigned)(g0 * 256.0);
        const unsigned long long f1 = (unsigned long long)(unsigned)(g1 * 256.0);
        const unsigned long long f2 = (unsigned long long)(unsigned)(g2 * 256.0);
        const unsigned long long f3 = (unsigned long long)(unsigned)(g3 * 256.0);
        fp[it] = f0 | (f1 << 16) | (f2 << 32) | (f3 << 48);
        __syncthreads();
    }
    #pragma unroll
    for (int off = 32; off; off >>= 1) {
        mn = fmin(mn, __shfl_xor(mn, off));
        mx = fmax(mx, __shfl_xor(mx, off));
    }
    if ((tid & 63) == 0) { smn[tid >> 6] = mn; smx[tid >> 6] = mx; }
    __syncthreads();
    if (tid == 0) {
        mm_part[bid * 2 + 0] = fmin(fmin(smn[0], smn[1]), fmin(smn[2], smn[3]));
        mm_part[bid * 2 + 1] = fmax(fmax(smx[0], smx[1]), fmax(smx[2], smx[3]));
    }
    grid.sync();

    // ---- phase 2: image min/max; histogram from register fids ----
    lh[tid] = 0u;
    if (tid < SEGS) {
        double a = mm_part[(img * SEGS + tid) * 2 + 0];
        double b = mm_part[(img * SEGS + tid) * 2 + 1];
        #pragma unroll
        for (int off = 8; off; off >>= 1) {
            a = fmin(a, __shfl_xor(a, off));
            b = fmax(b, __shfl_xor(b, off));
        }
        if (tid == 0) { sdm[0] = a; sdm[1] = b; }
    }
    __syncthreads();
    const double imn = sdm[0];
    const double s   = 256.0 / fmax(__dsub_rn(sdm[1], imn), 1e-12);
    #pragma unroll
    for (int it = 0; it < TILES; ++it) {
        const unsigned long long pk = fp[it];
        #pragma unroll
        for (int j = 0; j < 4; ++j) {
            const unsigned f = (unsigned)(pk >> (16 * j)) & 0xFFFFu;
            const double glo = (double)f * FINV;          // exact
            const double ghi = (double)(f + 1) * FINV;    // exact
            const int clo = bin_of(glo, imn, s);
            const int chi = bin_of(ghi, imn, s);
            int id;
            if (clo == chi) id = clo;
            else {  // boundary fine-bin (~0.4%): recompute exact gray
                const int64_t p = (int64_t)img * HW + (int64_t)(seg * TILES + it) * 1024
                                + 4 * tid + j;
                id = bin_of(gray_of(x[3 * p], x[3 * p + 1], x[3 * p + 2]), imn, s);
            }
            atomicAdd(&lh[id], 1u);
        }
    }
    __syncthreads();
    hist_part[bid * NBINS + tid] = lh[tid];
    grid.sync();

    // ---- phase 3: seg==0 blocks run the bit-exact parallel f64 Otsu ----
    if (seg == 0) {
        unsigned hu = 0;
        for (int c = 0; c < SEGS; ++c) hu += hist_part[(img * SEGS + c) * NBINS + tid];
        __syncthreads();   // union region reuse (lh -> hh)
        hh[tid] = (double)hu;
        __syncthreads();
        const double rng  = fmax(__dsub_rn(sdm[1], imn), 1e-12);
        const double step = rng / 256.0;
        double w1 = 0.0, hc1 = 0.0;
        for (int j = 0; j <= tid; ++j) {
            const double c = __dadd_rn(imn, __dmul_rn((double)j + 0.5, step));
            w1  = __dadd_rn(w1, hh[j]);
            hc1 = __dadd_rn(hc1, __dmul_rn(hh[j], c));
        }
        const double m1 = hc1 / fmax(w1, 1e-12);
        double w2 = 0.0, hc2 = 0.0;
        for (int j = NBINS - 1; j >= tid; --j) {
            const double c = __dadd_rn(imn, __dmul_rn((double)j + 0.5, step));
            w2  = __dadd_rn(w2, hh[j]);
            hc2 = __dadd_rn(hc2, __dmul_rn(hh[j], c));
        }
        w2s[tid] = w2;
        m2s[tid] = hc2 / fmax(w2, 1e-12);
        __syncthreads();
        if (tid < NBINS - 1) {
            const double d = __dsub_rn(m1, m2s[tid + 1]);
            vv[tid] = __dmul_rn(__dmul_rn(w1, w2s[tid + 1]), __dmul_rn(d, d));
        }
        __syncthreads();
        if (tid == 0) {
            double best = -1.0; int bi = 0;
            for (int i = 0; i < NBINS - 1; ++i)
                if (vv[i] > best) { best = vv[i]; bi = i; }  // first-occurrence argmax
            thr[img] = __dadd_rn(imn, __dmul_rn((double)bi + 0.5, step));
        }
    }
    grid.sync();

    // ---- phase 4: binarize from register fids; coalesced broadcast store ----
    const double T = thr[img];
    #pragma unroll
    for (int it = 0; it < TILES; ++it) {
        const unsigned long long pk = fp[it];
        float bb[4];
        #pragma unroll
        for (int j = 0; j < 4; ++j) {
            const unsigned f = (unsigned)(pk >> (16 * j)) & 0xFFFFu;
            const double glo = (double)f * FINV;          // g >= glo
            const double ghi = (double)(f + 1) * FINV;    // g <  ghi
            float r;
            if (glo > T)       r = 255.f;
            else if (ghi <= T) r = 0.f;
            else {  // threshold inside fine bin (rare): recompute exact gray
                const int64_t p = (int64_t)img * HW + (int64_t)(seg * TILES + it) * 1024
                                + 4 * tid + j;
                const double g = gray_of(x[3 * p], x[3 * p + 1], x[3 * p + 2]);
                r = (g > T) ? 255.f : 0.f;
            }
            bb[j] = r;
        }
        __syncthreads();   // bst region free (previous tile's stores issued)
        *(float4*)&bst[4 * tid] = make_float4(bb[0], bb[1], bb[2], bb[3]);
        __syncthreads();
        const int64_t ob4 = seg4 + (int64_t)it * 768;
        #pragma unroll
        for (int k = 0; k < 3; ++k) {
            const int q  = k * 256 + tid;
            const int p0 = (int)(((unsigned)(q * 4) * 21846u) >> 16);   // (4q)/3
            const int m  = q - 3 * (int)(((unsigned)q * 21846u) >> 16); // q%3
            const float lo = bst[p0];
            const float hi = bst[p0 + 1 < 1024 ? p0 + 1 : 1023];
            float4 o;
            o.x = lo;
            o.y = (m + 1 >= 3) ? hi : lo;
            o.z = (m + 2 >= 3) ? hi : lo;
            o.w = (m + 3 >= 3) ? hi : lo;
            ov[ob4 + q] = o;
        }
    }
}

// ============================ fallback (round-7, verified) ============================
template <bool WF>
__global__ __launch_bounds__(256) void k_minmax(const float* __restrict__ x,
                                                double* __restrict__ mm_part,
                                                unsigned long long* __restrict__ fid4) {
    __shared__ float st[STW];
    __shared__ double smn[4], smx[4];
    const int tid = threadIdx.x;
    const int img = blockIdx.x >> 6;
    const int blk = blockIdx.x & 63;
    const int64_t img4 = (int64_t)img * (HW * 3 / 4);
    const float4* xv = (const float4*)x;
    double mn = 1e300, mx = -1e300;
    for (int it = 0; it < 4; ++it) {
        const int tl = blk * 4 + it;
        stage3(xv, img4 + (int64_t)tl * 768, st, tid);
        __syncthreads();
        const float4 R = *(const float4*)&st[RB + 4 * tid];
        const float4 G = *(const float4*)&st[GB + 4 * tid];
        const float4 B = *(const float4*)&st[BB + 4 * tid];
        const double g0 = gray_of(R.x, G.x, B.x), g1 = gray_of(R.y, G.y, B.y),
                     g2 = gray_of(R.z, G.z, B.z), g3 = gray_of(R.w, G.w, B.w);
        mn = fmin(mn, fmin(fmin(g0, g1), fmin(g2, g3)));
        mx = fmax(mx, fmax(fmax(g0, g1), fmax(g2, g3)));
        if (WF) {
            const unsigned long long f0 = (unsigned long long)(unsigned)(g0 * 256.0);
            const unsigned long long f1 = (unsigned long long)(unsigned)(g1 * 256.0);
            const unsigned long long f2 = (unsigned long long)(unsigned)(g2 * 256.0);
            const unsigned long long f3 = (unsigned long long)(unsigned)(g3 * 256.0);
            fid4[img * (HW / 4) + tl * 256 + tid] = f0 | (f1 << 16) | (f2 << 32) | (f3 << 48);
        }
        __syncthreads();
    }
    #pragma unroll
    for (int off = 32; off; off >>= 1) {
        mn = fmin(mn, __shfl_xor(mn, off));
        mx = fmax(mx, __shfl_xor(mx, off));
    }
    if ((tid & 63) == 0) { smn[tid >> 6] = mn; smx[tid >> 6] = mx; }
    __syncthreads();
    if (tid == 0) {
        mn = fmin(fmin(smn[0], smn[1]), fmin(smn[2], smn[3]));
        mx = fmax(fmax(smx[0], smx[1]), fmax(smx[2], smx[3]));
        mm_part[(img * MMB + blk) * 2 + 0] = mn;
        mm_part[(img * MMB + blk) * 2 + 1] = mx;
    }
}

__device__ __forceinline__ void mm_reduce(const double* __restrict__ mm_part, int img,
                                          int tid, double* __restrict__ sdm) {
    if (tid < 64) {
        double mn = mm_part[(img * MMB + tid) * 2 + 0];
        double mx = mm_part[(img * MMB + tid) * 2 + 1];
        #pragma unroll
        for (int off = 32; off; off >>= 1) {
            mn = fmin(mn, __shfl_xor(mn, off));
            mx = fmax(mx, __shfl_xor(mx, off));
        }
        if (tid == 0) { sdm[0] = mn; sdm[1] = mx; }
    }
}

__global__ __launch_bounds__(256) void k_hist_fb(const unsigned long long* __restrict__ fid4,
        const float* __restrict__ x, const double* __restrict__ mm_part,
        unsigned* __restrict__ hist_part) {
    __shared__ unsigned lh[NBINS];
    __shared__ double sdm[2];
    const int tid = threadIdx.x;
    const int img = blockIdx.x >> 5;
    const int blk = blockIdx.x & 31;
    lh[tid] = 0u;
    mm_reduce(mm_part, img, tid, sdm);
    __syncthreads();
    const double mn = sdm[0];
    const double s  = 256.0 / fmax(__dsub_rn(sdm[1], mn), 1e-12);
    for (int it = 0; it < 8; ++it) {
        const int tl = blk * 8 + it;
        const unsigned long long pk = fid4[img * (HW / 4) + tl * 256 + tid];
        #pragma unroll
        for (int j = 0; j < 4; ++j) {
            const unsigned f = (unsigned)(pk >> (16 * j)) & 0xFFFFu;
            const int clo = bin_of((double)f * FINV, mn, s);
            const int chi = bin_of((double)(f + 1) * FINV, mn, s);
            int id;
            if (clo == chi) id = clo;
            else {
                const int64_t p = (int64_t)img * HW + (int64_t)tl * 1024 + 4 * tid + j;
                id = bin_of(gray_of(x[3 * p], x[3 * p + 1], x[3 * p + 2]), mn, s);
            }
            atomicAdd(&lh[id], 1u);
        }
    }
    __syncthreads();
    hist_part[(img * HB + blk) * NBINS + tid] = lh[tid];
}

__global__ void k_otsu_fb(const unsigned* __restrict__ hist_part,
                          const double* __restrict__ mm_part,
                          double* __restrict__ thr) {
    __shared__ double h[NBINS], w2s[NBINS], m2s[NBINS], vv[NBINS];
    __shared__ double sdm[2];
    const int img = blockIdx.x, t = threadIdx.x;
    mm_reduce(mm_part, img, t, sdm);
    unsigned hu = 0;
    for (int b = 0; b < HB; ++b) hu += hist_part[(img * HB + b) * NBINS + t];
    h[t] = (double)hu;
    __syncthreads();
    const double mn   = sdm[0];
    const double rng  = fmax(__dsub_rn(sdm[1], mn), 1e-12);
    const double step = rng / 256.0;
    double w1 = 0.0, hc1 = 0.0;
    for (int j = 0; j <= t; ++j) {
        const double c = __dadd_rn(mn, __dmul_rn((double)j + 0.5, step));
        w1  = __dadd_rn(w1, h[j]);
        hc1 = __dadd_rn(hc1, __dmul_rn(h[j], c));
    }
    const double m1 = hc1 / fmax(w1, 1e-12);
    double w2 = 0.0, hc2 = 0.0;
    for (int j = NBINS - 1; j >= t; --j) {
        const double c = __dadd_rn(mn, __dmul_rn((double)j + 0.5, step));
        w2  = __dadd_rn(w2, h[j]);
        hc2 = __dadd_rn(hc2, __dmul_rn(h[j], c));
    }
    w2s[t] = w2;
    m2s[t] = hc2 / fmax(w2, 1e-12);
    __syncthreads();
    if (t < NBINS - 1) {
        const double d = __dsub_rn(m1, m2s[t + 1]);
        vv[t] = __dmul_rn(__dmul_rn(w1, w2s[t + 1]), __dmul_rn(d, d));
    }
    __syncthreads();
    if (t == 0) {
        double best = -1.0; int bi = 0;
        for (int i = 0; i < NBINS - 1; ++i)
            if (vv[i] > best) { best = vv[i]; bi = i; }
        thr[img] = __dadd_rn(mn, __dmul_rn((double)bi + 0.5, step));
    }
}

__global__ __launch_bounds__(256) void k_binarize_fb(const unsigned long long* __restrict__ fid4,
        const float* __restrict__ x, const double* __restrict__ thr,
        float* __restrict__ out) {
    __shared__ float bst[1024];
    const int tid = threadIdx.x;
    const int img = blockIdx.x >> 6;
    const int blk = blockIdx.x & 63;
    const double T = thr[img];
    const int64_t img4 = (int64_t)img * (HW * 3 / 4);
    float4* ov = (float4*)out;
    for (int it = 0; it < 4; ++it) {
        const int tl = blk * 4 + it;
        const unsigned long long pk = fid4[img * (HW / 4) + tl * 256 + tid];
        float bb[4];
        #pragma unroll
        for (int j = 0; j < 4; ++j) {
            const unsigned f = (unsigned)(pk >> (16 * j)) & 0xFFFFu;
            const double glo = (double)f * FINV;
            const double ghi = (double)(f + 1) * FINV;
            float r;
            if (glo > T)       r = 255.f;
            else if (ghi <= T) r = 0.f;
            else {
                const int64_t p = (int64_t)img * HW + (int64_t)tl * 1024 + 4 * tid + j;
                const double g = gray_of(x[3 * p], x[3 * p + 1], x[3 * p + 2]);
                r = (g > T) ? 255.f : 0.f;
            }
            bb[j] = r;
        }
        __syncthreads();
        *(float4*)&bst[4 * tid] = make_float4(bb[0], bb[1], bb[2], bb[3]);
        __syncthreads();
        const int64_t ob4 = img4 + (int64_t)tl * 768;
        #pragma unroll
        for (int k = 0; k < 3; ++k) {
            const int q  = k * 256 + tid;
            const int p0 = (int)(((unsigned)(q * 4) * 21846u) >> 16);
            const int m  = q - 3 * (int)(((unsigned)q * 21846u) >> 16);
            const float lo = bst[p0];
            const float hi = bst[p0 + 1 < 1024 ? p0 + 1 : 1023];
            float4 o;
            o.x = lo;
            o.y = (m + 1 >= 3) ? hi : lo;
            o.z = (m + 2 >= 3) ? hi : lo;
            o.w = (m + 3 >= 3) ? hi : lo;
            ov[ob4 + q] = o;
        }
    }
}

extern "C" void kernel_launch(void* const* d_in, const int* in_sizes, int n_in,
                              void* d_out, int out_size, void* d_ws, size_t ws_size,
                              hipStream_t stream) {
    const float* x = (const float*)d_in[0];
    float* out = (float*)d_out;
    uint8_t* ws = (uint8_t*)d_ws;

    // ws: [0,512) thr f64 | [1024,66560) mm_part f64 (coop: 2048 d; fb: 64*64*2 d)
    //     [66560,2163712) hist_part u32 (coop: 1024*256; fb: 64*32*256)
    //     [2163712, +32MiB) fid4 (fallback only)
    double*             thr       = (double*)(ws);
    double*             mm_part   = (double*)(ws + 1024);
    unsigned*           hist_part = (unsigned*)(ws + 66560);
    unsigned long long* fid4      = (unsigned long long*)(ws + 2163712);

    void* args[] = {(void*)&x, (void*)&mm_part, (void*)&hist_part, (void*)&thr, (void*)&out};
    hipError_t e = hipLaunchCooperativeKernel((const void*)k_fused, dim3(GRID), dim3(256),
                                              args, 0, stream);
    if (e == hipSuccess) return;

    // fallback: verified round-7 4-kernel path
    (void)hipGetLastError();  // clear sticky error
    k_minmax<true><<<NIMG * MMB, 256, 0, stream>>>(x, mm_part, fid4);
    k_hist_fb<<<NIMG * HB, 256, 0, stream>>>(fid4, x, mm_part, hist_part);
    k_otsu_fb<<<NIMG, 256, 0, stream>>>(hist_part, mm_part, thr);
    k_binarize_fb<<<NIMG * MMB, 256, 0, stream>>>(fid4, x, thr, out);
}

// Round 9
// 163.107 us; speedup vs baseline: 4.0808x; 4.0808x over previous
//
#include <hip/hip_runtime.h>
#include <stdint.h>

#define NBINS 256
#define HW    (512 * 512)
#define NIMG  64
#define MMB   64   // K1/K3 blocks per image (4 tiles each)
#define HB    32   // K2 blocks per image (8 tiles each)
#define STW   3072 // AoS tile words (1024 px * 3 ch) = 12 KB
#define FINV  0.00390625  // 2^-8, exact

#if defined(__has_builtin)
# if __has_builtin(__builtin_amdgcn_global_load_lds)
#  define HAVE_GLL 1
# endif
#endif
#ifndef HAVE_GLL
# define HAVE_GLL 0
#endif

// f64 grayscale, exact op order verified bit-exact vs np reference (rounds 3-7):
__device__ __forceinline__ double gray_of(float r, float g, float b) {
    return fma((double)b, (double)0.1140f,
           fma((double)g, (double)0.5870f,
               (double)r * (double)0.2989f));
}

// Stage one 1024-px tile LINEARLY (AoS) into LDS: 768 float4, lane-coalesced.
// global_load_lds requires linear lane-order LDS dest (m104) -> AoS, not SoA.
__device__ __forceinline__ void stage_lin(const float* __restrict__ tp,
                                          float* __restrict__ st, int tid) {
#if HAVE_GLL
    #pragma unroll
    for (int k = 0; k < 3; ++k) {
        const float* g = tp + (k * 256 + tid) * 4;
        __builtin_amdgcn_global_load_lds(
            (__attribute__((address_space(1))) void*)(void*)g,
            (__attribute__((address_space(3))) void*)(void*)(st + (k * 256 + tid) * 4),
            16, 0, 0);
    }
#else
    #pragma unroll
    for (int k = 0; k < 3; ++k) {
        const float4 v = ((const float4*)tp)[k * 256 + tid];
        *(float4*)&st[(k * 256 + tid) * 4] = v;
    }
#endif
}

// K1: 64 blocks/img x 4 tiles; min/max partials + u16 fine-index (fid) emit.
// fid = trunc(g*256.0): power-of-two scale is EXACT in f64 ->
// g in [fid/256,(fid+1)/256) with exact endpoints (round-7 proof, absmax 0).
// Pixel mapping: thread tid owns px = tid + 256*j of its tile (strided:
// 3-word LDS reads are 2-lanes/bank = conflict-free per m136).
__global__ __launch_bounds__(256) void k_minmax(const float* __restrict__ x,
        double* __restrict__ mm_part, unsigned long long* __restrict__ fid4) {
    __shared__ float st[STW];
    __shared__ double smn[4], smx[4];
    const int tid = threadIdx.x;
    const int img = blockIdx.x >> 6;
    const int blk = blockIdx.x & 63;
    const int64_t imgf = (int64_t)img * ((int64_t)HW * 3);
    double mn = 1e300, mx = -1e300;
    for (int it = 0; it < 4; ++it) {
        const int tl = blk * 4 + it;
        stage_lin(x + imgf + (int64_t)tl * 3072, st, tid);
        __syncthreads();   // drains vmcnt (global_load_lds) per compiler barrier semantics
        unsigned long long pk = 0;
        #pragma unroll
        for (int j = 0; j < 4; ++j) {
            const int w = 3 * tid + 768 * j;
            const double g = gray_of(st[w], st[w + 1], st[w + 2]);
            mn = fmin(mn, g);
            mx = fmax(mx, g);
            pk |= (unsigned long long)(unsigned)(g * 256.0) << (16 * j);
        }
        fid4[img * (HW / 4) + tl * 256 + tid] = pk;
        __syncthreads();   // st reusable next tile
    }
    #pragma unroll
    for (int off = 32; off; off >>= 1) {
        mn = fmin(mn, __shfl_xor(mn, off));
        mx = fmax(mx, __shfl_xor(mx, off));
    }
    if ((tid & 63) == 0) { smn[tid >> 6] = mn; smx[tid >> 6] = mx; }
    __syncthreads();
    if (tid == 0) {
        mn = fmin(fmin(smn[0], smn[1]), fmin(smn[2], smn[3]));
        mx = fmax(fmax(smx[0], smx[1]), fmax(smx[2], smx[3]));
        mm_part[(img * MMB + blk) * 2 + 0] = mn;
        mm_part[(img * MMB + blk) * 2 + 1] = mx;
    }
}

// wave-0 reduce of the 64 min/max partials (exact; order-insensitive)
__device__ __forceinline__ void mm_reduce(const double* __restrict__ mm_part, int img,
                                          int tid, double* __restrict__ sdm) {
    if (tid < 64) {
        double mn = mm_part[(img * MMB + tid) * 2 + 0];
        double mx = mm_part[(img * MMB + tid) * 2 + 1];
        #pragma unroll
        for (int off = 32; off; off >>= 1) {
            mn = fmin(mn, __shfl_xor(mn, off));
            mx = fmax(mx, __shfl_xor(mx, off));
        }
        if (tid == 0) { sdm[0] = mn; sdm[1] = mx; }
    }
}

__device__ __forceinline__ int bin_of(double g, double mn, double s) {
    int id = (int)__dmul_rn(__dsub_rn(g, mn), s);  // trunc = astype(int32)
    return id < 0 ? 0 : (id > 255 ? 255 : id);
}

// K2: 32 blocks/img x 8 tiles: histogram partials from fid (33 MB, L3-resident).
// Monotone bracket: same coarse bin for both exact endpoints -> exact;
// else (~0.4%) gather-recompute exact gray.
__global__ __launch_bounds__(256) void k_hist(const unsigned long long* __restrict__ fid4,
        const float* __restrict__ x, const double* __restrict__ mm_part,
        unsigned* __restrict__ hist_part) {
    __shared__ unsigned lh[NBINS];
    __shared__ double sdm[2];
    const int tid = threadIdx.x;
    const int img = blockIdx.x >> 5;
    const int blk = blockIdx.x & 31;
    lh[tid] = 0u;
    mm_reduce(mm_part, img, tid, sdm);
    __syncthreads();
    const double mn = sdm[0];
    const double s  = 256.0 / fmax(__dsub_rn(sdm[1], mn), 1e-12);
    for (int it = 0; it < 8; ++it) {
        const int tl = blk * 8 + it;
        const unsigned long long pk = fid4[img * (HW / 4) + tl * 256 + tid];
        #pragma unroll
        for (int j = 0; j < 4; ++j) {
            const unsigned f = (unsigned)(pk >> (16 * j)) & 0xFFFFu;
            const int clo = bin_of((double)f * FINV, mn, s);
            const int chi = bin_of((double)(f + 1) * FINV, mn, s);
            int id;
            if (clo == chi) id = clo;
            else {  // boundary fine-bin: recompute exact gray (rare)
                const int64_t p = (int64_t)img * HW + (int64_t)tl * 1024 + tid + 256 * j;
                id = bin_of(gray_of(x[3 * p], x[3 * p + 1], x[3 * p + 2]), mn, s);
            }
            atomicAdd(&lh[id], 1u);
        }
    }
    __syncthreads();
    hist_part[(img * HB + blk) * NBINS + tid] = lh[tid];
}

// K3: 64 blocks/img x 4 tiles. Each block recomputes the bit-exact f64 Otsu
// from the per-image partials (identical ops -> bit-identical T across blocks;
// partials are L2-resident), then binarizes from the fid bracket with
// LDS-broadcast coalesced 16 B/lane output stores.
__global__ __launch_bounds__(256) void k_bin(const unsigned long long* __restrict__ fid4,
        const float* __restrict__ x, const double* __restrict__ mm_part,
        const unsigned* __restrict__ hist_part, float* __restrict__ out) {
    __shared__ double h[NBINS], w2s[NBINS], m2s[NBINS], vv[NBINS];
    __shared__ double sdm[2];
    __shared__ double sT;
    __shared__ float bst[1024];
    const int tid = threadIdx.x;
    const int img = blockIdx.x >> 6;
    const int blk = blockIdx.x & 63;
    mm_reduce(mm_part, img, tid, sdm);
    unsigned hu = 0;
    for (int b = 0; b < HB; ++b) hu += hist_part[(img * HB + b) * NBINS + tid];  // exact int
    h[tid] = (double)hu;
    __syncthreads();
    const double mn   = sdm[0];
    const double rng  = fmax(__dsub_rn(sdm[1], mn), 1e-12);
    const double step = rng / 256.0;
    // per-thread ordered partial sums == numpy serial cumsum, bit-exact (verified r4-7)
    double w1 = 0.0, hc1 = 0.0;
    for (int j = 0; j <= tid; ++j) {
        const double c = __dadd_rn(mn, __dmul_rn((double)j + 0.5, step));
        w1  = __dadd_rn(w1, h[j]);
        hc1 = __dadd_rn(hc1, __dmul_rn(h[j], c));
    }
    const double m1 = hc1 / fmax(w1, 1e-12);
    double w2 = 0.0, hc2 = 0.0;
    for (int j = NBINS - 1; j >= tid; --j) {
        const double c = __dadd_rn(mn, __dmul_rn((double)j + 0.5, step));
        w2  = __dadd_rn(w2, h[j]);
        hc2 = __dadd_rn(hc2, __dmul_rn(h[j], c));
    }
    w2s[tid] = w2;
    m2s[tid] = hc2 / fmax(w2, 1e-12);
    __syncthreads();
    if (tid < NBINS - 1) {
        const double d = __dsub_rn(m1, m2s[tid + 1]);
        vv[tid] = __dmul_rn(__dmul_rn(w1, w2s[tid + 1]), __dmul_rn(d, d));
    }
    __syncthreads();
    if (tid == 0) {
        double best = -1.0; int bi = 0;
        for (int i = 0; i < NBINS - 1; ++i)
            if (vv[i] > best) { best = vv[i]; bi = i; }   // first-occurrence argmax
        sT = __dadd_rn(mn, __dmul_rn((double)bi + 0.5, step));
    }
    __syncthreads();
    const double T = sT;
    const int64_t img4 = (int64_t)img * (HW * 3 / 4);
    float4* ov = (float4*)out;
    for (int it = 0; it < 4; ++it) {
        const int tl = blk * 4 + it;
        const unsigned long long pk = fid4[img * (HW / 4) + tl * 256 + tid];
        #pragma unroll
        for (int j = 0; j < 4; ++j) {
            const unsigned f = (unsigned)(pk >> (16 * j)) & 0xFFFFu;
            const double glo = (double)f * FINV;          // exact, g >= glo
            const double ghi = (double)(f + 1) * FINV;    // exact, g <  ghi
            float r;
            if (glo > T)       r = 255.f;
            else if (ghi <= T) r = 0.f;
            else {  // threshold inside fine bin (rare): recompute exact gray
                const int64_t p = (int64_t)img * HW + (int64_t)tl * 1024 + tid + 256 * j;
                const double g = gray_of(x[3 * p], x[3 * p + 1], x[3 * p + 2]);
                r = (g > T) ? 255.f : 0.f;
            }
            bst[tid + 256 * j] = r;   // stride-256 scalar: 2 lanes/bank, free
        }
        __syncthreads();
        const int64_t ob4 = img4 + (int64_t)tl * 768;
        #pragma unroll
        for (int k = 0; k < 3; ++k) {
            const int q  = k * 256 + tid;
            const int p0 = (int)(((unsigned)(q * 4) * 21846u) >> 16);   // (4q)/3
            const int m  = q - 3 * (int)(((unsigned)q * 21846u) >> 16); // q%3
            const float lo = bst[p0];
            const float hi = bst[p0 + 1 < 1024 ? p0 + 1 : 1023];
            float4 o;
            o.x = lo;
            o.y = (m + 1 >= 3) ? hi : lo;
            o.z = (m + 2 >= 3) ? hi : lo;
            o.w = (m + 3 >= 3) ? hi : lo;
            ov[ob4 + q] = o;   // 16 B/lane, fully coalesced (round-5 lesson)
        }
        __syncthreads();
    }
}

extern "C" void kernel_launch(void* const* d_in, const int* in_sizes, int n_in,
                              void* d_out, int out_size, void* d_ws, size_t ws_size,
                              hipStream_t stream) {
    const float* x = (const float*)d_in[0];
    float* out = (float*)d_out;
    uint8_t* ws = (uint8_t*)d_ws;

    // ws: [0,65536) mm_part f64 | [65536, +2MiB) hist_part u32 | [2162688, +32MiB) fid4
    double*             mm_part   = (double*)(ws);
    unsigned*           hist_part = (unsigned*)(ws + 65536);
    unsigned long long* fid4      = (unsigned long long*)(ws + 2162688);

    k_minmax<<<NIMG * MMB, 256, 0, stream>>>(x, mm_part, fid4);
    k_hist<<<NIMG * HB, 256, 0, stream>>>(fid4, x, mm_part, hist_part);
    k_bin<<<NIMG * MMB, 256, 0, stream>>>(fid4, x, mm_part, hist_part, out);
}